// Round 17
// baseline (105.606 us; speedup 1.0000x reference)
//
#include <hip/hip_runtime.h>
#include <math.h>

#ifndef M_PI
#define M_PI 3.14159265358979323846
#endif

constexpr int N    = 1024;
constexpr int M    = 4096;
constexpr int RANK = 32;
constexpr float PHI1 = -1.5339807878856412e-3f;   // -2*pi/4096

typedef __attribute__((ext_vector_type(8))) short bf16x8;
typedef __attribute__((ext_vector_type(4))) float f32x4;

__device__ __forceinline__ float softplus_f(float x) {
    return (x > 0.0f) ? (x + log1pf(__expf(-x))) : log1pf(__expf(x));
}

__device__ __forceinline__ short bf16_rne(float x) {
    unsigned u = __float_as_uint(x);
    u = (u + 0x7fffu + ((u >> 16) & 1u)) >> 16;
    return (short)u;
}

// ===========================================================================
// DFT stage 1: G[d][r][k0] = sum_k1 sp(h[d][64k1+k0]) e^{-2pi i k1 r/64}
// grid (8 rG, 32 d), block 256.  (validated R10-R16)
// ===========================================================================
__global__ __launch_bounds__(256) void dft_s1(const float* __restrict__ H,
                                              float* __restrict__ GR,
                                              float* __restrict__ GI) {
    __shared__ float sh[M];              // 16 KB
    const int d = blockIdx.y, tid = threadIdx.x;
    const float4* H4 = (const float4*)(H + d * M);
    for (int i = tid; i < M / 4; i += 256) {
        const float4 v = H4[i];
        ((float4*)sh)[i] = make_float4(softplus_f(v.x), softplus_f(v.y),
                                       softplus_f(v.z), softplus_f(v.w));
    }
    __syncthreads();

    const int k0 = tid & 63;
    const int r0 = blockIdx.x * 8 + (tid >> 6) * 2;
    float twR0 = 1.f, twI0 = 0.f, aR0 = 0.f, aI0 = 0.f;
    float twR1 = 1.f, twI1 = 0.f, aR1 = 0.f, aI1 = 0.f;
    float s0, c0, s1, c1;
    __sincosf((-2.0f * (float)M_PI / 64.0f) * (float)r0,       &s0, &c0);
    __sincosf((-2.0f * (float)M_PI / 64.0f) * (float)(r0 + 1), &s1, &c1);

    for (int k1 = 0; k1 < 64; ++k1) {
        const float h = sh[(k1 << 6) + k0];
        aR0 = fmaf(h, twR0, aR0);  aI0 = fmaf(h, twI0, aI0);
        aR1 = fmaf(h, twR1, aR1);  aI1 = fmaf(h, twI1, aI1);
        float nR = fmaf(twR0, c0, -twI0 * s0);
        float nI = fmaf(twR0, s0,  twI0 * c0);
        twR0 = nR; twI0 = nI;
        nR = fmaf(twR1, c1, -twI1 * s1);
        nI = fmaf(twR1, s1,  twI1 * c1);
        twR1 = nR; twI1 = nI;
    }
    const int base = d * 4096 + r0 * 64 + k0;
    GR[base]      = aR0;  GI[base]      = aI0;
    GR[base + 64] = aR1;  GI[base + 64] = aI1;
}

// ===========================================================================
// DFT stage 2: Hf[d][m] = sum_k0 G[d][m&63][k0] e^{-2pi i k0 m/4096}
// grid (16 mG, 32 d), block 256.  (validated R10-R16)
// ===========================================================================
__global__ __launch_bounds__(256) void dft_s2(const float* __restrict__ GR,
                                              const float* __restrict__ GI,
                                              float* __restrict__ HfR,
                                              float* __restrict__ HfI) {
    __shared__ float sGR[64 * 65], sGI[64 * 65];   // 33.3 KB
    const int d = blockIdx.y, tid = threadIdx.x;
    const float4* gr4 = (const float4*)(GR + d * 4096);
    const float4* gi4 = (const float4*)(GI + d * 4096);
    for (int i4 = tid; i4 < 1024; i4 += 256) {
        const int r = i4 >> 4, k0 = (i4 & 15) << 2;
        const float4 vr = gr4[i4];
        const float4 vi = gi4[i4];
        const int p = r * 65 + k0;
        sGR[p] = vr.x; sGR[p+1] = vr.y; sGR[p+2] = vr.z; sGR[p+3] = vr.w;
        sGI[p] = vi.x; sGI[p+1] = vi.y; sGI[p+2] = vi.z; sGI[p+3] = vi.w;
    }
    __syncthreads();

    const int m = blockIdx.x * 256 + tid;
    const int rb = (m & 63) * 65;
    float ss, sc; __sincosf(PHI1 * (float)m, &ss, &sc);
    float tR_ = 1.f, tI_ = 0.f, accR = 0.f, accI = 0.f;
    #pragma unroll 8
    for (int k0 = 0; k0 < 64; ++k0) {
        const float gr = sGR[rb + k0], gi = sGI[rb + k0];
        accR = fmaf(tR_, gr, fmaf(-tI_, gi, accR));
        accI = fmaf(tR_, gi, fmaf( tI_, gr, accI));
        const float nR = fmaf(tR_, sc, -tI_ * ss);
        const float nI = fmaf(tR_, ss,  tI_ * sc);
        tR_ = nR; tI_ = nI;
    }
    HfR[d * M + m] = accR;
    HfI[d * M + m] = accI;
}

// ===========================================================================
// MFMA einsum — EXACT R15 version (MT=128, validated 93.6 us, absmax 1024).
// Launched TWICE this round (idempotent) to measure its true duration:
// dur_us - 93.6 = T_mfma.
// ===========================================================================
__global__ __launch_bounds__(256) void einsum_mfma(const float* __restrict__ W,
                                                   const float* __restrict__ tau,
                                                   const float* __restrict__ HfR,
                                                   const float* __restrict__ HfI,
                                                   float* __restrict__ out_f) {
    __shared__ float sR[128][36], sI[128][36];   // 36.9 KB
    const int tid   = threadIdx.x;
    const int mBase = blockIdx.x * 128;
    const int nBase = blockIdx.y * 64;

    for (int e = tid; e < 1024; e += 256) {
        const int d = e & 31, g = e >> 5;
        const float4 vr = *(const float4*)(HfR + d * M + mBase + (g << 2));
        const float4 vi = *(const float4*)(HfI + d * M + mBase + (g << 2));
        sR[(g << 2) + 0][d] = vr.x;  sI[(g << 2) + 0][d] = vi.x;
        sR[(g << 2) + 1][d] = vr.y;  sI[(g << 2) + 1][d] = vi.y;
        sR[(g << 2) + 2][d] = vr.z;  sI[(g << 2) + 2][d] = vi.z;
        sR[(g << 2) + 3][d] = vr.w;  sI[(g << 2) + 3][d] = vi.w;
    }

    const int wv = tid >> 6, lane = tid & 63;
    const int q = lane >> 4, l = lane & 15;
    const int nA = nBase + wv * 16 + l;
    const int d8 = q << 3;
    const float mcF = (float)(mBase + 64);

    const float4 w0 = *(const float4*)(W   + nA * RANK + d8);
    const float4 w1 = *(const float4*)(W   + nA * RANK + d8 + 4);
    const float4 t0 = *(const float4*)(tau + nA * RANK + d8);
    const float4 t1 = *(const float4*)(tau + nA * RANK + d8 + 4);
    const float wj[8] = {w0.x,w0.y,w0.z,w0.w,w1.x,w1.y,w1.z,w1.w};
    const float tj[8] = {t0.x,t0.y,t0.z,t0.w,t1.x,t1.y,t1.z,t1.w};

    bf16x8 fA[6];
    #pragma unroll
    for (int j = 0; j < 8; ++j) {
        const float sw = softplus_f(wj[j]);
        const float a1 = PHI1 * tj[j];
        float s0, c0; __sincosf(a1 * mcF, &s0, &c0);
        const float R0 = sw * c0,          I0 = sw * s0;
        const float R1 = -a1 * I0,         I1 = a1 * R0;
        const float h  = 0.5f * a1;
        const float R2 = -h * I1,          I2 = h * R1;
        fA[0][j] = bf16_rne(R0);  fA[1][j] = bf16_rne(-I0);
        fA[2][j] = bf16_rne(R1);  fA[3][j] = bf16_rne(-I1);
        fA[4][j] = bf16_rne(R2);  fA[5][j] = bf16_rne(-I2);
    }
    __syncthreads();

    for (int mt = 0; mt < 8; ++mt) {
        const int mL = (mt << 4) + l;
        const float dlt = (float)mL - 64.0f;
        const float d2  = dlt * dlt;
        const float4 r0 = *(const float4*)&sR[mL][d8];
        const float4 r1 = *(const float4*)&sR[mL][d8 + 4];
        const float4 i0 = *(const float4*)&sI[mL][d8];
        const float4 i1 = *(const float4*)&sI[mL][d8 + 4];
        const float hr[8] = {r0.x,r0.y,r0.z,r0.w,r1.x,r1.y,r1.z,r1.w};
        const float hi[8] = {i0.x,i0.y,i0.z,i0.w,i1.x,i1.y,i1.z,i1.w};

        bf16x8 b0, b1, b2, b3, b4, b5;
        #pragma unroll
        for (int j = 0; j < 8; ++j) {
            b0[j] = bf16_rne(hr[j]);
            b1[j] = bf16_rne(hi[j]);
            b2[j] = bf16_rne(hr[j] * dlt);
            b3[j] = bf16_rne(hi[j] * dlt);
            b4[j] = bf16_rne(hr[j] * d2);
            b5[j] = bf16_rne(hi[j] * d2);
        }
        f32x4 acc = {0.f, 0.f, 0.f, 0.f};
        acc = __builtin_amdgcn_mfma_f32_16x16x32_bf16(fA[0], b0, acc, 0, 0, 0);
        acc = __builtin_amdgcn_mfma_f32_16x16x32_bf16(fA[1], b1, acc, 0, 0, 0);
        acc = __builtin_amdgcn_mfma_f32_16x16x32_bf16(fA[2], b2, acc, 0, 0, 0);
        acc = __builtin_amdgcn_mfma_f32_16x16x32_bf16(fA[3], b3, acc, 0, 0, 0);
        acc = __builtin_amdgcn_mfma_f32_16x16x32_bf16(fA[4], b4, acc, 0, 0, 0);
        acc = __builtin_amdgcn_mfma_f32_16x16x32_bf16(fA[5], b5, acc, 0, 0, 0);

        #pragma unroll
        for (int r = 0; r < 4; ++r)
            out_f[(size_t)(nBase + wv * 16 + (q << 2) + r) * M
                  + mBase + (mt << 4) + l] = acc[r];
    }
}

// ===========================================================================
// dft_fused (no-ws fallback only — validated R5-R9).
// ===========================================================================
__global__ __launch_bounds__(256) void dft_fused(const float* __restrict__ H,
                                                 float* __restrict__ HfR,
                                                 float* __restrict__ HfI) {
    __shared__ float  sh[M];
    __shared__ float2 sG[64 * 65];
    const int d = blockIdx.y, tid = threadIdx.x;
    for (int k = tid; k < M; k += 256) sh[k] = softplus_f(H[d * M + k]);
    __syncthreads();

    const int k0 = tid & 63;
    const int rB = (tid >> 6) * 16;
    float twR[16], twI[16], stR[16], stI[16], aR[16], aI[16];
    #pragma unroll
    for (int rr = 0; rr < 16; ++rr) {
        const float ang = (-2.0f * (float)M_PI / 64.0f) * (float)(rB + rr);
        __sincosf(ang, &stI[rr], &stR[rr]);
        twR[rr] = 1.f; twI[rr] = 0.f; aR[rr] = 0.f; aI[rr] = 0.f;
    }
    for (int k1 = 0; k1 < 64; ++k1) {
        const float h = sh[(k1 << 6) + k0];
        #pragma unroll
        for (int rr = 0; rr < 16; ++rr) {
            aR[rr] = fmaf(h, twR[rr], aR[rr]);
            aI[rr] = fmaf(h, twI[rr], aI[rr]);
            const float nR = fmaf(twR[rr], stR[rr], -twI[rr] * stI[rr]);
            const float nI = fmaf(twR[rr], stI[rr],  twI[rr] * stR[rr]);
            twR[rr] = nR; twI[rr] = nI;
        }
    }
    #pragma unroll
    for (int rr = 0; rr < 16; ++rr)
        sG[k0 * 65 + rB + rr] = make_float2(aR[rr], aI[rr]);
    __syncthreads();

    const int mBase = blockIdx.x * 1024;
    for (int j = 0; j < 4; ++j) {
        const int m = mBase + j * 256 + tid;
        const int r = m & 63;
        float ss, sc; __sincosf(PHI1 * (float)m, &ss, &sc);
        float tR_ = 1.f, tI_ = 0.f, accR = 0.f, accI = 0.f;
        #pragma unroll 8
        for (int qq = 0; qq < 64; ++qq) {
            const float2 g = sG[qq * 65 + r];
            accR = fmaf(tR_, g.x, fmaf(-tI_, g.y, accR));
            accI = fmaf(tR_, g.y, fmaf( tI_, g.x, accI));
            const float nR = fmaf(tR_, sc, -tI_ * ss);
            const float nI = fmaf(tR_, ss,  tI_ * sc);
            tR_ = nR; tI_ = nI;
        }
        HfR[d * M + m] = accR;
        HfI[d * M + m] = accI;
    }
}

// ===========================================================================
// VALU einsum v8 (validated R13) — kept for cplx / fallback paths.
// ===========================================================================
template <bool CPLX, int U>
__global__ __launch_bounds__(256) void einsum_kernel(const float* __restrict__ W,
                                                     const float* __restrict__ tau,
                                                     const float* __restrict__ HfR,
                                                     const float* __restrict__ HfI,
                                                     float* __restrict__ out_f) {
    constexpr int ROWS = 16 * U;
    constexpr int MT   = 128;
    __shared__ float2 sHf[16 * MT];
    __shared__ float  sW[ROWS][RANK], sT[ROWS][RANK];
    const int tid   = threadIdx.x;
    const int mBase = blockIdx.x * MT;
    const int nBase = blockIdx.y * ROWS;

    for (int i = tid; i < ROWS * RANK; i += 256) {
        const int n_ = i >> 5, dd = i & 31;
        sW[n_][dd] = softplus_f(W[(nBase + n_) * RANK + dd]);
        sT[n_][dd] = tau[(nBase + n_) * RANK + dd];
    }

    const int nl = tid >> 4, chunk = tid & 15;
    const int m0 = mBase + (chunk << 3);

    float accR[U][8], accI[U][8];
    #pragma unroll
    for (int u = 0; u < U; ++u)
        #pragma unroll
        for (int j = 0; j < 8; ++j) { accR[u][j] = 0.f; if (CPLX) accI[u][j] = 0.f; }

    for (int half = 0; half < 2; ++half) {
        __syncthreads();
        for (int e = tid; e < 16 * 64; e += 256) {
            const int dl = e >> 6, p = e & 63;
            const int mm = p << 1;
            const int base = (half * 16 + dl) * M + mBase + mm;
            const float2 r2 = *(const float2*)(HfR + base);
            const float2 q2 = *(const float2*)(HfI + base);
            const int c = mm >> 3, j0 = mm & 7;
            float2* s2 = sHf + (dl << 7);
            s2[(j0 << 4) + c]       = make_float2(r2.x, q2.x);
            s2[((j0 + 1) << 4) + c] = make_float2(r2.y, q2.y);
        }
        __syncthreads();

        #pragma unroll 1
        for (int dl = 0; dl < 16; ++dl) {
            const int dd = (half << 4) + dl;
            float aR_[U], aI_[U], bR_[U], bI_[U], K[U];
            #pragma unroll
            for (int u = 0; u < U; ++u) {
                const float t = sT[nl * U + u][dd], w = sW[nl * U + u][dd];
                const float a1 = PHI1 * t;
                float sp, cp; __sincosf(a1, &sp, &cp);
                float s0, c0; __sincosf(a1 * (float)m0, &s0, &c0);
                aR_[u] = w * c0;
                aI_[u] = w * s0;
                bR_[u] = fmaf(aR_[u], cp, -aI_[u] * sp);
                bI_[u] = fmaf(aI_[u], cp,  aR_[u] * sp);
                K[u]   = 2.0f * cp;
            }
            int idx = (dl << 7) + chunk;
            #pragma unroll
            for (int j = 0; j < 8; ++j) {
                const float2 h = sHf[idx];
                #pragma unroll
                for (int u = 0; u < U; ++u) {
                    accR[u][j] = fmaf(aR_[u], h.x, fmaf(-aI_[u], h.y, accR[u][j]));
                    if (CPLX) accI[u][j] = fmaf(aR_[u], h.y, fmaf(aI_[u], h.x, accI[u][j]));
                    const float nR = fmaf(K[u], bR_[u], -aR_[u]);
                    const float nI = fmaf(K[u], bI_[u], -aI_[u]);
                    aR_[u] = bR_[u]; aI_[u] = bI_[u];
                    bR_[u] = nR;     bI_[u] = nI;
                }
                idx += 16;
            }
        }
    }

    #pragma unroll
    for (int u = 0; u < U; ++u) {
        const int n = nBase + nl * U + u;
        if (CPLX) {
            float2* o2 = ((float2*)out_f) + (size_t)n * M + m0;
            #pragma unroll
            for (int qq = 0; qq < 4; ++qq)
                ((float4*)o2)[qq] = make_float4(accR[u][2*qq], accI[u][2*qq],
                                                accR[u][2*qq+1], accI[u][2*qq+1]);
        } else {
            float* op = out_f + (size_t)n * M + m0;
            ((float4*)op)[0] = make_float4(accR[u][0], accR[u][1], accR[u][2], accR[u][3]);
            ((float4*)op)[1] = make_float4(accR[u][4], accR[u][5], accR[u][6], accR[u][7]);
        }
    }
}

// ===========================================================================
// Tail kernels (no-ws fallback only — dead given 268 MB ws).
// ===========================================================================
__global__ __launch_bounds__(256) void tail_real(const float* __restrict__ W,
                                                 const float* __restrict__ tau,
                                                 const float* __restrict__ stashR,
                                                 const float* __restrict__ stashI,
                                                 float* __restrict__ out_f) {
    __shared__ float stR[32 * 32], stI[32 * 32];
    __shared__ float sW[64][RANK], sT[64][RANK];
    const int tid = threadIdx.x;
    const int c0  = blockIdx.x * 32;
    const int nBase = N - 64;
    for (int i = tid; i < 64 * RANK; i += 256) {
        const int n_ = i >> 5, dd = i & 31;
        sW[n_][dd] = softplus_f(W[(nBase + n_) * RANK + dd]);
        sT[n_][dd] = tau[(nBase + n_) * RANK + dd];
    }
    for (int i = tid; i < 32 * 32; i += 256) {
        const int d_ = i >> 5, mm = i & 31;
        stR[i] = stashR[d_ * M + c0 + mm];
        stI[i] = stashI[d_ * M + c0 + mm];
    }
    __syncthreads();
    const int n = tid >> 2, chunk = tid & 3;
    const int m0 = c0 + chunk;
    float acc[8];
    #pragma unroll
    for (int j = 0; j < 8; ++j) acc[j] = 0.f;
    for (int d = 0; d < RANK; ++d) {
        const float t = sT[n][d], w = sW[n][d];
        const float a1 = PHI1 * t;
        float ss, sc; __sincosf(a1 * 4.0f, &ss, &sc);
        float s0, c0f; __sincosf(a1 * (float)m0, &s0, &c0f);
        float tR_ = w * c0f, tI_ = w * s0;
        int idx = (d << 5) + chunk;
        #pragma unroll
        for (int j = 0; j < 8; ++j) {
            acc[j] = fmaf(tR_, stR[idx], fmaf(-tI_, stI[idx], acc[j]));
            const float nR = fmaf(tR_, sc, -tI_ * ss);
            const float nI = fmaf(tR_, ss,  tI_ * sc);
            tR_ = nR; tI_ = nI;
            idx += 4;
        }
    }
    #pragma unroll
    for (int j = 0; j < 8; ++j)
        out_f[(size_t)(nBase + n) * M + m0 + (j << 2)] = acc[j];
}

__global__ __launch_bounds__(256) void tail_cplx(const float* __restrict__ W,
                                                 const float* __restrict__ tau,
                                                 const float* __restrict__ stashR,
                                                 const float* __restrict__ stashI,
                                                 float* __restrict__ out_f) {
    const int nBase = N - 32;
    __shared__ float sW[32][RANK], sT[32][RANK];
    const int tid = threadIdx.x, mBase = blockIdx.x * 256;
    for (int i = tid; i < 32 * RANK; i += 256) {
        const int n_ = i >> 5, dd = i & 31;
        sW[n_][dd] = softplus_f(W[(nBase + n_) * RANK + dd]);
        sT[n_][dd] = tau[(nBase + n_) * RANK + dd];
    }
    const int m = mBase + tid;
    float hr[RANK], hi[RANK];
    #pragma unroll
    for (int d = 0; d < RANK; ++d) { hr[d] = stashR[d * M + m]; hi[d] = stashI[d * M + m]; }
    __syncthreads();
    const float phi = PHI1 * (float)m;
    for (int n_ = 0; n_ < 32; ++n_) {
        float aR = 0.f, aI = 0.f;
        #pragma unroll
        for (int d = 0; d < RANK; ++d) {
            const float t = sT[n_][d], w = sW[n_][d];
            float s, c; __sincosf(t * phi, &s, &c);
            const float cw = c * w, sw = s * w;
            aR = fmaf(cw, hr[d], fmaf(-sw, hi[d], aR));
            aI = fmaf(cw, hi[d], fmaf( sw, hr[d], aI));
        }
        ((float2*)out_f)[(size_t)(nBase + n_) * M + m] = make_float2(aR, aI);
    }
}

// ---------------------------------------------------------------------------
extern "C" void kernel_launch(void* const* d_in, const int* in_sizes, int n_in,
                              void* d_out, int out_size, void* d_ws, size_t ws_size,
                              hipStream_t stream) {
    const float* W   = (const float*)d_in[0];
    const float* H   = (const float*)d_in[1];
    const float* tau = (const float*)d_in[2];
    float* out_f = (float*)d_out;

    const bool   cplx   = (out_size >= 2 * N * M);
    const size_t planeN = (size_t)RANK * M;            // 131072 floats / plane

    if (d_ws != nullptr && ws_size >= 4 * planeN * sizeof(float)) {
        float* HfR = (float*)d_ws;
        float* HfI = HfR + planeN;
        float* GR  = HfI + planeN;
        float* GI  = GR  + planeN;
        dft_s1<<<dim3(8, 32), 256, 0, stream>>>(H, GR, GI);
        dft_s2<<<dim3(16, 32), 256, 0, stream>>>(GR, GI, HfR, HfI);
        if (cplx) {
            einsum_kernel<true , 2><<<dim3(32, N / 32), 256, 0, stream>>>(W, tau, HfR, HfI, out_f);
        } else {
            // MEASUREMENT: double launch (idempotent). dur - 93.6 = T_mfma.
            einsum_mfma<<<dim3(32, 16), 256, 0, stream>>>(W, tau, HfR, HfI, out_f);
            einsum_mfma<<<dim3(32, 16), 256, 0, stream>>>(W, tau, HfR, HfI, out_f);
        }
    } else if (!cplx) {
        float* HfR = out_f + (size_t)(N - 64) * M;     // stash in last 64 real rows
        float* HfI = HfR + planeN;
        dft_fused<<<dim3(4, 32), 256, 0, stream>>>(H, HfR, HfI);
        einsum_kernel<false, 2><<<dim3(32, (N - 64) / 32), 256, 0, stream>>>(W, tau, HfR, HfI, out_f);
        tail_real<<<dim3(128), 256, 0, stream>>>(W, tau, HfR, HfI, out_f);
    } else {
        float* HfR = out_f + 2 * (size_t)N * M - 2 * planeN;  // last 32 cplx rows
        float* HfI = HfR + planeN;
        dft_fused<<<dim3(4, 32), 256, 0, stream>>>(H, HfR, HfI);
        einsum_kernel<true , 2><<<dim3(32, (N - 32) / 32), 256, 0, stream>>>(W, tau, HfR, HfI, out_f);
        tail_cplx<<<dim3(16), 256, 0, stream>>>(W, tau, HfR, HfI, out_f);
    }
}

// Round 18
// 90.959 us; speedup vs baseline: 1.1610x; 1.1610x over previous
//
#include <hip/hip_runtime.h>
#include <math.h>

#ifndef M_PI
#define M_PI 3.14159265358979323846
#endif

constexpr int N    = 1024;
constexpr int M    = 4096;
constexpr int RANK = 32;
constexpr float PHI1 = -1.5339807878856412e-3f;   // -2*pi/4096

typedef __attribute__((ext_vector_type(8))) short bf16x8;
typedef __attribute__((ext_vector_type(4))) float f32x4;

__device__ __forceinline__ float softplus_f(float x) {
    return (x > 0.0f) ? (x + log1pf(__expf(-x))) : log1pf(__expf(x));
}

__device__ __forceinline__ short bf16_rne(float x) {
    unsigned u = __float_as_uint(x);
    u = (u + 0x7fffu + ((u >> 16) & 1u)) >> 16;
    return (short)u;
}

// ===========================================================================
// DFT stage 1: G[d][r][k0] = sum_k1 sp(h[d][64k1+k0]) e^{-2pi i k1 r/64}
// grid (8 rG, 32 d), block 256.  (validated R10-R17)
// ===========================================================================
__global__ __launch_bounds__(256) void dft_s1(const float* __restrict__ H,
                                              float* __restrict__ GR,
                                              float* __restrict__ GI) {
    __shared__ float sh[M];              // 16 KB
    const int d = blockIdx.y, tid = threadIdx.x;
    const float4* H4 = (const float4*)(H + d * M);
    for (int i = tid; i < M / 4; i += 256) {
        const float4 v = H4[i];
        ((float4*)sh)[i] = make_float4(softplus_f(v.x), softplus_f(v.y),
                                       softplus_f(v.z), softplus_f(v.w));
    }
    __syncthreads();

    const int k0 = tid & 63;
    const int r0 = blockIdx.x * 8 + (tid >> 6) * 2;
    float twR0 = 1.f, twI0 = 0.f, aR0 = 0.f, aI0 = 0.f;
    float twR1 = 1.f, twI1 = 0.f, aR1 = 0.f, aI1 = 0.f;
    float s0, c0, s1, c1;
    __sincosf((-2.0f * (float)M_PI / 64.0f) * (float)r0,       &s0, &c0);
    __sincosf((-2.0f * (float)M_PI / 64.0f) * (float)(r0 + 1), &s1, &c1);

    for (int k1 = 0; k1 < 64; ++k1) {
        const float h = sh[(k1 << 6) + k0];
        aR0 = fmaf(h, twR0, aR0);  aI0 = fmaf(h, twI0, aI0);
        aR1 = fmaf(h, twR1, aR1);  aI1 = fmaf(h, twI1, aI1);
        float nR = fmaf(twR0, c0, -twI0 * s0);
        float nI = fmaf(twR0, s0,  twI0 * c0);
        twR0 = nR; twI0 = nI;
        nR = fmaf(twR1, c1, -twI1 * s1);
        nI = fmaf(twR1, s1,  twI1 * c1);
        twR1 = nR; twI1 = nI;
    }
    const int base = d * 4096 + r0 * 64 + k0;
    GR[base]      = aR0;  GI[base]      = aI0;
    GR[base + 64] = aR1;  GI[base + 64] = aI1;
}

// ===========================================================================
// DFT stage 2: Hf[d][m] = sum_k0 G[d][m&63][k0] e^{-2pi i k0 m/4096}
// grid (16 mG, 32 d), block 256.  (validated R10-R17)
// ===========================================================================
__global__ __launch_bounds__(256) void dft_s2(const float* __restrict__ GR,
                                              const float* __restrict__ GI,
                                              float* __restrict__ HfR,
                                              float* __restrict__ HfI) {
    __shared__ float sGR[64 * 65], sGI[64 * 65];   // 33.3 KB
    const int d = blockIdx.y, tid = threadIdx.x;
    const float4* gr4 = (const float4*)(GR + d * 4096);
    const float4* gi4 = (const float4*)(GI + d * 4096);
    for (int i4 = tid; i4 < 1024; i4 += 256) {
        const int r = i4 >> 4, k0 = (i4 & 15) << 2;
        const float4 vr = gr4[i4];
        const float4 vi = gi4[i4];
        const int p = r * 65 + k0;
        sGR[p] = vr.x; sGR[p+1] = vr.y; sGR[p+2] = vr.z; sGR[p+3] = vr.w;
        sGI[p] = vi.x; sGI[p+1] = vi.y; sGI[p+2] = vi.z; sGI[p+3] = vi.w;
    }
    __syncthreads();

    const int m = blockIdx.x * 256 + tid;
    const int rb = (m & 63) * 65;
    float ss, sc; __sincosf(PHI1 * (float)m, &ss, &sc);
    float tR_ = 1.f, tI_ = 0.f, accR = 0.f, accI = 0.f;
    #pragma unroll 8
    for (int k0 = 0; k0 < 64; ++k0) {
        const float gr = sGR[rb + k0], gi = sGI[rb + k0];
        accR = fmaf(tR_, gr, fmaf(-tI_, gi, accR));
        accI = fmaf(tR_, gi, fmaf( tI_, gr, accI));
        const float nR = fmaf(tR_, sc, -tI_ * ss);
        const float nI = fmaf(tR_, ss,  tI_ * sc);
        tR_ = nR; tI_ = nI;
    }
    HfR[d * M + m] = accR;
    HfI[d * M + m] = accI;
}

// ===========================================================================
// MFMA einsum — EXACT R15 version (MT=128, validated 93.6 us, absmax 1024).
// Single launch (R17's measurement double-launch reverted).
// ===========================================================================
__global__ __launch_bounds__(256) void einsum_mfma(const float* __restrict__ W,
                                                   const float* __restrict__ tau,
                                                   const float* __restrict__ HfR,
                                                   const float* __restrict__ HfI,
                                                   float* __restrict__ out_f) {
    __shared__ float sR[128][36], sI[128][36];   // 36.9 KB
    const int tid   = threadIdx.x;
    const int mBase = blockIdx.x * 128;
    const int nBase = blockIdx.y * 64;

    for (int e = tid; e < 1024; e += 256) {
        const int d = e & 31, g = e >> 5;
        const float4 vr = *(const float4*)(HfR + d * M + mBase + (g << 2));
        const float4 vi = *(const float4*)(HfI + d * M + mBase + (g << 2));
        sR[(g << 2) + 0][d] = vr.x;  sI[(g << 2) + 0][d] = vi.x;
        sR[(g << 2) + 1][d] = vr.y;  sI[(g << 2) + 1][d] = vi.y;
        sR[(g << 2) + 2][d] = vr.z;  sI[(g << 2) + 2][d] = vi.z;
        sR[(g << 2) + 3][d] = vr.w;  sI[(g << 2) + 3][d] = vi.w;
    }

    const int wv = tid >> 6, lane = tid & 63;
    const int q = lane >> 4, l = lane & 15;
    const int nA = nBase + wv * 16 + l;
    const int d8 = q << 3;
    const float mcF = (float)(mBase + 64);

    const float4 w0 = *(const float4*)(W   + nA * RANK + d8);
    const float4 w1 = *(const float4*)(W   + nA * RANK + d8 + 4);
    const float4 t0 = *(const float4*)(tau + nA * RANK + d8);
    const float4 t1 = *(const float4*)(tau + nA * RANK + d8 + 4);
    const float wj[8] = {w0.x,w0.y,w0.z,w0.w,w1.x,w1.y,w1.z,w1.w};
    const float tj[8] = {t0.x,t0.y,t0.z,t0.w,t1.x,t1.y,t1.z,t1.w};

    bf16x8 fA[6];
    #pragma unroll
    for (int j = 0; j < 8; ++j) {
        const float sw = softplus_f(wj[j]);
        const float a1 = PHI1 * tj[j];
        float s0, c0; __sincosf(a1 * mcF, &s0, &c0);
        const float R0 = sw * c0,          I0 = sw * s0;
        const float R1 = -a1 * I0,         I1 = a1 * R0;
        const float h  = 0.5f * a1;
        const float R2 = -h * I1,          I2 = h * R1;
        fA[0][j] = bf16_rne(R0);  fA[1][j] = bf16_rne(-I0);
        fA[2][j] = bf16_rne(R1);  fA[3][j] = bf16_rne(-I1);
        fA[4][j] = bf16_rne(R2);  fA[5][j] = bf16_rne(-I2);
    }
    __syncthreads();

    for (int mt = 0; mt < 8; ++mt) {
        const int mL = (mt << 4) + l;
        const float dlt = (float)mL - 64.0f;
        const float d2  = dlt * dlt;
        const float4 r0 = *(const float4*)&sR[mL][d8];
        const float4 r1 = *(const float4*)&sR[mL][d8 + 4];
        const float4 i0 = *(const float4*)&sI[mL][d8];
        const float4 i1 = *(const float4*)&sI[mL][d8 + 4];
        const float hr[8] = {r0.x,r0.y,r0.z,r0.w,r1.x,r1.y,r1.z,r1.w};
        const float hi[8] = {i0.x,i0.y,i0.z,i0.w,i1.x,i1.y,i1.z,i1.w};

        bf16x8 b0, b1, b2, b3, b4, b5;
        #pragma unroll
        for (int j = 0; j < 8; ++j) {
            b0[j] = bf16_rne(hr[j]);
            b1[j] = bf16_rne(hi[j]);
            b2[j] = bf16_rne(hr[j] * dlt);
            b3[j] = bf16_rne(hi[j] * dlt);
            b4[j] = bf16_rne(hr[j] * d2);
            b5[j] = bf16_rne(hi[j] * d2);
        }
        f32x4 acc = {0.f, 0.f, 0.f, 0.f};
        acc = __builtin_amdgcn_mfma_f32_16x16x32_bf16(fA[0], b0, acc, 0, 0, 0);
        acc = __builtin_amdgcn_mfma_f32_16x16x32_bf16(fA[1], b1, acc, 0, 0, 0);
        acc = __builtin_amdgcn_mfma_f32_16x16x32_bf16(fA[2], b2, acc, 0, 0, 0);
        acc = __builtin_amdgcn_mfma_f32_16x16x32_bf16(fA[3], b3, acc, 0, 0, 0);
        acc = __builtin_amdgcn_mfma_f32_16x16x32_bf16(fA[4], b4, acc, 0, 0, 0);
        acc = __builtin_amdgcn_mfma_f32_16x16x32_bf16(fA[5], b5, acc, 0, 0, 0);

        #pragma unroll
        for (int r = 0; r < 4; ++r)
            out_f[(size_t)(nBase + wv * 16 + (q << 2) + r) * M
                  + mBase + (mt << 4) + l] = acc[r];
    }
}

// ===========================================================================
// dft_fused (no-ws fallback only — validated R5-R9).
// ===========================================================================
__global__ __launch_bounds__(256) void dft_fused(const float* __restrict__ H,
                                                 float* __restrict__ HfR,
                                                 float* __restrict__ HfI) {
    __shared__ float  sh[M];
    __shared__ float2 sG[64 * 65];
    const int d = blockIdx.y, tid = threadIdx.x;
    for (int k = tid; k < M; k += 256) sh[k] = softplus_f(H[d * M + k]);
    __syncthreads();

    const int k0 = tid & 63;
    const int rB = (tid >> 6) * 16;
    float twR[16], twI[16], stR[16], stI[16], aR[16], aI[16];
    #pragma unroll
    for (int rr = 0; rr < 16; ++rr) {
        const float ang = (-2.0f * (float)M_PI / 64.0f) * (float)(rB + rr);
        __sincosf(ang, &stI[rr], &stR[rr]);
        twR[rr] = 1.f; twI[rr] = 0.f; aR[rr] = 0.f; aI[rr] = 0.f;
    }
    for (int k1 = 0; k1 < 64; ++k1) {
        const float h = sh[(k1 << 6) + k0];
        #pragma unroll
        for (int rr = 0; rr < 16; ++rr) {
            aR[rr] = fmaf(h, twR[rr], aR[rr]);
            aI[rr] = fmaf(h, twI[rr], aI[rr]);
            const float nR = fmaf(twR[rr], stR[rr], -twI[rr] * stI[rr]);
            const float nI = fmaf(twR[rr], stI[rr],  twI[rr] * stR[rr]);
            twR[rr] = nR; twI[rr] = nI;
        }
    }
    #pragma unroll
    for (int rr = 0; rr < 16; ++rr)
        sG[k0 * 65 + rB + rr] = make_float2(aR[rr], aI[rr]);
    __syncthreads();

    const int mBase = blockIdx.x * 1024;
    for (int j = 0; j < 4; ++j) {
        const int m = mBase + j * 256 + tid;
        const int r = m & 63;
        float ss, sc; __sincosf(PHI1 * (float)m, &ss, &sc);
        float tR_ = 1.f, tI_ = 0.f, accR = 0.f, accI = 0.f;
        #pragma unroll 8
        for (int qq = 0; qq < 64; ++qq) {
            const float2 g = sG[qq * 65 + r];
            accR = fmaf(tR_, g.x, fmaf(-tI_, g.y, accR));
            accI = fmaf(tR_, g.y, fmaf( tI_, g.x, accI));
            const float nR = fmaf(tR_, sc, -tI_ * ss);
            const float nI = fmaf(tR_, ss,  tI_ * sc);
            tR_ = nR; tI_ = nI;
        }
        HfR[d * M + m] = accR;
        HfI[d * M + m] = accI;
    }
}

// ===========================================================================
// VALU einsum v8 (validated R13) — kept for cplx / fallback paths.
// ===========================================================================
template <bool CPLX, int U>
__global__ __launch_bounds__(256) void einsum_kernel(const float* __restrict__ W,
                                                     const float* __restrict__ tau,
                                                     const float* __restrict__ HfR,
                                                     const float* __restrict__ HfI,
                                                     float* __restrict__ out_f) {
    constexpr int ROWS = 16 * U;
    constexpr int MT   = 128;
    __shared__ float2 sHf[16 * MT];
    __shared__ float  sW[ROWS][RANK], sT[ROWS][RANK];
    const int tid   = threadIdx.x;
    const int mBase = blockIdx.x * MT;
    const int nBase = blockIdx.y * ROWS;

    for (int i = tid; i < ROWS * RANK; i += 256) {
        const int n_ = i >> 5, dd = i & 31;
        sW[n_][dd] = softplus_f(W[(nBase + n_) * RANK + dd]);
        sT[n_][dd] = tau[(nBase + n_) * RANK + dd];
    }

    const int nl = tid >> 4, chunk = tid & 15;
    const int m0 = mBase + (chunk << 3);

    float accR[U][8], accI[U][8];
    #pragma unroll
    for (int u = 0; u < U; ++u)
        #pragma unroll
        for (int j = 0; j < 8; ++j) { accR[u][j] = 0.f; if (CPLX) accI[u][j] = 0.f; }

    for (int half = 0; half < 2; ++half) {
        __syncthreads();
        for (int e = tid; e < 16 * 64; e += 256) {
            const int dl = e >> 6, p = e & 63;
            const int mm = p << 1;
            const int base = (half * 16 + dl) * M + mBase + mm;
            const float2 r2 = *(const float2*)(HfR + base);
            const float2 q2 = *(const float2*)(HfI + base);
            const int c = mm >> 3, j0 = mm & 7;
            float2* s2 = sHf + (dl << 7);
            s2[(j0 << 4) + c]       = make_float2(r2.x, q2.x);
            s2[((j0 + 1) << 4) + c] = make_float2(r2.y, q2.y);
        }
        __syncthreads();

        #pragma unroll 1
        for (int dl = 0; dl < 16; ++dl) {
            const int dd = (half << 4) + dl;
            float aR_[U], aI_[U], bR_[U], bI_[U], K[U];
            #pragma unroll
            for (int u = 0; u < U; ++u) {
                const float t = sT[nl * U + u][dd], w = sW[nl * U + u][dd];
                const float a1 = PHI1 * t;
                float sp, cp; __sincosf(a1, &sp, &cp);
                float s0, c0; __sincosf(a1 * (float)m0, &s0, &c0);
                aR_[u] = w * c0;
                aI_[u] = w * s0;
                bR_[u] = fmaf(aR_[u], cp, -aI_[u] * sp);
                bI_[u] = fmaf(aI_[u], cp,  aR_[u] * sp);
                K[u]   = 2.0f * cp;
            }
            int idx = (dl << 7) + chunk;
            #pragma unroll
            for (int j = 0; j < 8; ++j) {
                const float2 h = sHf[idx];
                #pragma unroll
                for (int u = 0; u < U; ++u) {
                    accR[u][j] = fmaf(aR_[u], h.x, fmaf(-aI_[u], h.y, accR[u][j]));
                    if (CPLX) accI[u][j] = fmaf(aR_[u], h.y, fmaf(aI_[u], h.x, accI[u][j]));
                    const float nR = fmaf(K[u], bR_[u], -aR_[u]);
                    const float nI = fmaf(K[u], bI_[u], -aI_[u]);
                    aR_[u] = bR_[u]; aI_[u] = bI_[u];
                    bR_[u] = nR;     bI_[u] = nI;
                }
                idx += 16;
            }
        }
    }

    #pragma unroll
    for (int u = 0; u < U; ++u) {
        const int n = nBase + nl * U + u;
        if (CPLX) {
            float2* o2 = ((float2*)out_f) + (size_t)n * M + m0;
            #pragma unroll
            for (int qq = 0; qq < 4; ++qq)
                ((float4*)o2)[qq] = make_float4(accR[u][2*qq], accI[u][2*qq],
                                                accR[u][2*qq+1], accI[u][2*qq+1]);
        } else {
            float* op = out_f + (size_t)n * M + m0;
            ((float4*)op)[0] = make_float4(accR[u][0], accR[u][1], accR[u][2], accR[u][3]);
            ((float4*)op)[1] = make_float4(accR[u][4], accR[u][5], accR[u][6], accR[u][7]);
        }
    }
}

// ===========================================================================
// Tail kernels (no-ws fallback only — dead given 268 MB ws).
// ===========================================================================
__global__ __launch_bounds__(256) void tail_real(const float* __restrict__ W,
                                                 const float* __restrict__ tau,
                                                 const float* __restrict__ stashR,
                                                 const float* __restrict__ stashI,
                                                 float* __restrict__ out_f) {
    __shared__ float stR[32 * 32], stI[32 * 32];
    __shared__ float sW[64][RANK], sT[64][RANK];
    const int tid = threadIdx.x;
    const int c0  = blockIdx.x * 32;
    const int nBase = N - 64;
    for (int i = tid; i < 64 * RANK; i += 256) {
        const int n_ = i >> 5, dd = i & 31;
        sW[n_][dd] = softplus_f(W[(nBase + n_) * RANK + dd]);
        sT[n_][dd] = tau[(nBase + n_) * RANK + dd];
    }
    for (int i = tid; i < 32 * 32; i += 256) {
        const int d_ = i >> 5, mm = i & 31;
        stR[i] = stashR[d_ * M + c0 + mm];
        stI[i] = stashI[d_ * M + c0 + mm];
    }
    __syncthreads();
    const int n = tid >> 2, chunk = tid & 3;
    const int m0 = c0 + chunk;
    float acc[8];
    #pragma unroll
    for (int j = 0; j < 8; ++j) acc[j] = 0.f;
    for (int d = 0; d < RANK; ++d) {
        const float t = sT[n][d], w = sW[n][d];
        const float a1 = PHI1 * t;
        float ss, sc; __sincosf(a1 * 4.0f, &ss, &sc);
        float s0, c0f; __sincosf(a1 * (float)m0, &s0, &c0f);
        float tR_ = w * c0f, tI_ = w * s0;
        int idx = (d << 5) + chunk;
        #pragma unroll
        for (int j = 0; j < 8; ++j) {
            acc[j] = fmaf(tR_, stR[idx], fmaf(-tI_, stI[idx], acc[j]));
            const float nR = fmaf(tR_, sc, -tI_ * ss);
            const float nI = fmaf(tR_, ss,  tI_ * sc);
            tR_ = nR; tI_ = nI;
            idx += 4;
        }
    }
    #pragma unroll
    for (int j = 0; j < 8; ++j)
        out_f[(size_t)(nBase + n) * M + m0 + (j << 2)] = acc[j];
}

__global__ __launch_bounds__(256) void tail_cplx(const float* __restrict__ W,
                                                 const float* __restrict__ tau,
                                                 const float* __restrict__ stashR,
                                                 const float* __restrict__ stashI,
                                                 float* __restrict__ out_f) {
    const int nBase = N - 32;
    __shared__ float sW[32][RANK], sT[32][RANK];
    const int tid = threadIdx.x, mBase = blockIdx.x * 256;
    for (int i = tid; i < 32 * RANK; i += 256) {
        const int n_ = i >> 5, dd = i & 31;
        sW[n_][dd] = softplus_f(W[(nBase + n_) * RANK + dd]);
        sT[n_][dd] = tau[(nBase + n_) * RANK + dd];
    }
    const int m = mBase + tid;
    float hr[RANK], hi[RANK];
    #pragma unroll
    for (int d = 0; d < RANK; ++d) { hr[d] = stashR[d * M + m]; hi[d] = stashI[d * M + m]; }
    __syncthreads();
    const float phi = PHI1 * (float)m;
    for (int n_ = 0; n_ < 32; ++n_) {
        float aR = 0.f, aI = 0.f;
        #pragma unroll
        for (int d = 0; d < RANK; ++d) {
            const float t = sT[n_][d], w = sW[n_][d];
            float s, c; __sincosf(t * phi, &s, &c);
            const float cw = c * w, sw = s * w;
            aR = fmaf(cw, hr[d], fmaf(-sw, hi[d], aR));
            aI = fmaf(cw, hi[d], fmaf( sw, hr[d], aI));
        }
        ((float2*)out_f)[(size_t)(nBase + n_) * M + m] = make_float2(aR, aI);
    }
}

// ---------------------------------------------------------------------------
extern "C" void kernel_launch(void* const* d_in, const int* in_sizes, int n_in,
                              void* d_out, int out_size, void* d_ws, size_t ws_size,
                              hipStream_t stream) {
    const float* W   = (const float*)d_in[0];
    const float* H   = (const float*)d_in[1];
    const float* tau = (const float*)d_in[2];
    float* out_f = (float*)d_out;

    const bool   cplx   = (out_size >= 2 * N * M);
    const size_t planeN = (size_t)RANK * M;            // 131072 floats / plane

    if (d_ws != nullptr && ws_size >= 4 * planeN * sizeof(float)) {
        float* HfR = (float*)d_ws;
        float* HfI = HfR + planeN;
        float* GR  = HfI + planeN;
        float* GI  = GR  + planeN;
        dft_s1<<<dim3(8, 32), 256, 0, stream>>>(H, GR, GI);
        dft_s2<<<dim3(16, 32), 256, 0, stream>>>(GR, GI, HfR, HfI);
        if (cplx)
            einsum_kernel<true , 2><<<dim3(32, N / 32), 256, 0, stream>>>(W, tau, HfR, HfI, out_f);
        else
            einsum_mfma<<<dim3(32, 16), 256, 0, stream>>>(W, tau, HfR, HfI, out_f);
    } else if (!cplx) {
        float* HfR = out_f + (size_t)(N - 64) * M;     // stash in last 64 real rows
        float* HfI = HfR + planeN;
        dft_fused<<<dim3(4, 32), 256, 0, stream>>>(H, HfR, HfI);
        einsum_kernel<false, 2><<<dim3(32, (N - 64) / 32), 256, 0, stream>>>(W, tau, HfR, HfI, out_f);
        tail_real<<<dim3(128), 256, 0, stream>>>(W, tau, HfR, HfI, out_f);
    } else {
        float* HfR = out_f + 2 * (size_t)N * M - 2 * planeN;  // last 32 cplx rows
        float* HfI = HfR + planeN;
        dft_fused<<<dim3(4, 32), 256, 0, stream>>>(H, HfR, HfI);
        einsum_kernel<true , 2><<<dim3(32, (N - 32) / 32), 256, 0, stream>>>(W, tau, HfR, HfI, out_f);
        tail_cplx<<<dim3(16), 256, 0, stream>>>(W, tau, HfR, HfI, out_f);
    }
}